// Round 9
// baseline (181.508 us; speedup 1.0000x reference)
//
#include <hip/hip_runtime.h>
#include <hip/hip_bf16.h>

#define B_   16
#define LQ_  2048
#define LK_  2048
#define D_   256
#define DV_  256
#define MINF -1.0e30f
#define VSTR 36          // padded V^T row stride (shorts): bank-conflict-free
#define VTS  9216        // shorts per 32-key V tile: 256 * VSTR

typedef __bf16 bf16x8_t __attribute__((ext_vector_type(8)));
typedef __bf16 bf16x4_t __attribute__((ext_vector_type(4)));
typedef short  s16x8    __attribute__((ext_vector_type(8)));
typedef short  s16x4    __attribute__((ext_vector_type(4)));
typedef float  f32x4    __attribute__((ext_vector_type(4)));

__device__ __forceinline__ unsigned short f2bf(float f) {
  unsigned int u = __builtin_bit_cast(unsigned int, f);
  u += 0x7fffu + ((u >> 16) & 1u);   // RNE (finite inputs)
  return (unsigned short)(u >> 16);
}

__device__ __forceinline__ s16x8 pack8(float4 a, float4 b) {
  s16x8 r;
  r[0] = (short)f2bf(a.x); r[1] = (short)f2bf(a.y);
  r[2] = (short)f2bf(a.z); r[3] = (short)f2bf(a.w);
  r[4] = (short)f2bf(b.x); r[5] = (short)f2bf(b.y);
  r[6] = (short)f2bf(b.z); r[7] = (short)f2bf(b.w);
  return r;
}

__device__ __forceinline__ void glds16(const unsigned short* g, unsigned short* l) {
  __builtin_amdgcn_global_load_lds(
      (const __attribute__((address_space(1))) unsigned int*)g,
      (__attribute__((address_space(3))) unsigned int*)l, 16, 0, 0);
}

// 16x16x16 bf16 MFMA (legacy "_1k" builtin name on gfx950)
__device__ __forceinline__ f32x4 mfma16(s16x4 a, s16x4 b, f32x4 c) {
#if __has_builtin(__builtin_amdgcn_mfma_f32_16x16x16bf16_1k)
  return __builtin_amdgcn_mfma_f32_16x16x16bf16_1k(a, b, c, 0, 0, 0);
#else
  f32x4 d;
  asm volatile("v_mfma_f32_16x16x16_bf16 %0, %1, %2, %3"
               : "=v"(d) : "v"(a), "v"(b), "v"(c));
  return d;
#endif
}

// ---------- prepass: K -> bf16, row-major, chunk-XOR pre-swizzled ----------
__global__ __launch_bounds__(256) void prep_k(const float* __restrict__ K,
                                              unsigned short* __restrict__ wsK) {
  int gid = blockIdx.x * 256 + threadIdx.x;
  int gr = gid >> 5;
  int c  = gid & 31;
  const float* src = K + ((size_t)gr << 8) + c * 8;
  float4 a = *(const float4*)(src);
  float4 b = *(const float4*)(src + 4);
  *(s16x8*)(wsK + ((size_t)gr << 8) + ((c ^ (gr & 7)) << 3)) = pack8(a, b);
}

// ---------- prepass: V -> bf16, transposed per 32-key tile, stride-36 pad ----
// ws[blk*VTS + dv*36 + k] = bf16(V[blk*32 + k][dv]); shorts 32..35 of each row pad
__global__ __launch_bounds__(256) void prep_v(const float* __restrict__ V,
                                              unsigned short* __restrict__ wsV) {
  __shared__ unsigned short t[256 * 40];        // [dv][32k + 8 pad]
  const int tid = threadIdx.x;
  const float* src = V + (size_t)blockIdx.x * 32 * 256;
  #pragma unroll
  for (int i = 0; i < 8; ++i) {
    int idx = i * 256 + tid;
    int k   = idx >> 6;
    int dv0 = (idx & 63) * 4;
    float4 x = *(const float4*)(src + k * 256 + dv0);
    t[(dv0 + 0) * 40 + k] = f2bf(x.x);
    t[(dv0 + 1) * 40 + k] = f2bf(x.y);
    t[(dv0 + 2) * 40 + k] = f2bf(x.z);
    t[(dv0 + 3) * 40 + k] = f2bf(x.w);
  }
  __syncthreads();
  unsigned short* dst = wsV + (size_t)blockIdx.x * VTS;
  #pragma unroll
  for (int i = 0; i < 4; ++i) {
    int idx = i * 256 + tid;
    int dv = idx >> 2;
    int cs = idx & 3;
    s16x4 lo = *(const s16x4*)(&t[dv * 40 + cs * 8]);
    s16x4 hi = *(const s16x4*)(&t[dv * 40 + cs * 8 + 4]);
    *(s16x4*)(dst + dv * VSTR + cs * 8)     = lo;   // 8B stores (72B rows)
    *(s16x4*)(dst + dv * VSTR + cs * 8 + 4) = hi;
  }
}

// ---------- prepass: sorted-pair schedule (longest batches paired w/ shortest) --
__global__ __launch_bounds__(256) void prep_sched(const int* __restrict__ VL,
                                                  int* __restrict__ sched) {
  __shared__ int ord[16];
  if (threadIdx.x == 0) {
    int nk[16], o[16];
    const int wide = (VL[1] == 0);
    for (int i = 0; i < 16; ++i) {
      int v = wide ? VL[2 * i] : VL[i];
      if (v < 1) v = 1;
      if (v > LK_) v = LK_;
      nk[i] = v; o[i] = i;
    }
    for (int i = 1; i < 16; ++i) {           // insertion sort, desc
      int key = o[i], kv = nk[key], j = i - 1;
      while (j >= 0 && nk[o[j]] < kv) { o[j + 1] = o[j]; --j; }
      o[j + 1] = key;
    }
    for (int i = 0; i < 16; ++i) ord[i] = o[i];
  }
  __syncthreads();
  for (int s = threadIdx.x; s < 512; s += 256) {
    int half = s >> 8;                       // 0: first fill wave, 1: second
    int i    = s & 255;
    int pos  = i >> 5;                       // 0..7
    int qt   = i & 31;
    int bsel = half ? ord[15 - pos] : ord[pos];
    sched[s] = bsel | (qt << 8);
  }
}

// ---------- main v9: 8 waves (4 rq x 2 kh), QB=64, KB=32, 68KB LDS ----------
// 2 blocks/CU; P in-lane; padded V (no PV conflicts); shfl-free softmax path.
__global__ __launch_bounds__(512, 4) void attn_fwd9(
    const float* __restrict__ Q, const unsigned short* __restrict__ wsK,
    const unsigned short* __restrict__ wsV, const int* __restrict__ VL,
    const int* __restrict__ sched, float* __restrict__ O) {
  // shorts: K dbuf [0,16384) ; V dbuf [16384, 34816)  (9216 each, stride-36 rows)
  __shared__ __align__(16) unsigned short lds_all[34816];   // 69632 B

  const int tid  = threadIdx.x;
  const int wid  = tid >> 6;
  const int lane = tid & 63;
  const int l15  = lane & 15;
  const int lg   = lane >> 4;
  const int rq   = wid & 3;        // q sub-tile (16 rows)
  const int kh   = wid >> 2;       // key half (16 keys) of the 32-key tile

  const int as  = sched[blockIdx.x];
  const int b   = as & 255;
  const int qt  = as >> 8;

  int n_k = (VL[1] == 0) ? VL[2 * b] : VL[b];
  if (n_k < 1) n_k = 1;
  if (n_k > LK_) n_k = LK_;
  const int nt = (n_k + 31) >> 5;

  const int qbase = qt * 64 + rq * 16;

  // Q fragments (B-operand): qf[dk] = Q[qbase+l15][dk*32 + lg*8 .. +8]
  s16x8 qf[8];
  {
    const float* qp = Q + ((size_t)b * LQ_ + qbase + l15) * D_ + lg * 8;
    #pragma unroll
    for (int dk = 0; dk < 8; ++dk) {
      float4 a = *(const float4*)(qp + dk * 32);
      float4 c = *(const float4*)(qp + dk * 32 + 4);
      qf[dk] = pack8(a, c);
    }
  }

  f32x4 o[16];
  #pragma unroll
  for (int c = 0; c < 16; ++c) o[c] = (f32x4){0.f, 0.f, 0.f, 0.f};
  float m = MINF, l = 0.f;   // l is a PER-LANE partial sum (reduced at end)

  const unsigned short* kbw = wsK + (size_t)b * LK_ * D_;
  const unsigned short* vbw = wsV + (size_t)b * 64 * VTS;

  // K: 1024 16B-chunks (2 passes); V: 1152 chunks (2 passes + waves 0,1 extra).
  // Per-wave loads: waves 0-1: 5, waves 2-7: 4 -> uniform vmcnt(4) is safe.
#define STAGE(buf, t) do {                                                    \
    const unsigned short* ks_ = kbw + (size_t)(t) * 8192;                     \
    const unsigned short* vs_ = vbw + (size_t)(t) * VTS;                      \
    _Pragma("unroll")                                                         \
    for (int p = 0; p < 2; ++p) {                                             \
      int cu = p * 512 + wid * 64;                                            \
      glds16(ks_ + (size_t)(cu + lane) * 8, &lds_all[(buf) * 8192 + cu * 8]); \
      glds16(vs_ + (size_t)(cu + lane) * 8,                                   \
             &lds_all[16384 + (buf) * VTS + cu * 8]);                         \
    }                                                                         \
    if (wid < 2) {                                                            \
      int cu = 1024 + wid * 64;                                               \
      glds16(vs_ + (size_t)(cu + lane) * 8,                                   \
             &lds_all[16384 + (buf) * VTS + cu * 8]);                         \
    }                                                                         \
  } while (0)

  STAGE(0, 0);

  for (int t = 0; t < nt; ++t) {
    const int cur = t & 1;
    if (t + 1 < nt) {
      STAGE(cur ^ 1, t + 1);
      asm volatile("s_waitcnt vmcnt(4)" ::: "memory");  // tile t landed
    } else {
      asm volatile("s_waitcnt vmcnt(0)" ::: "memory");
    }
    __builtin_amdgcn_s_barrier();
    __builtin_amdgcn_sched_barrier(0);

    // ---- S^T = K Q^T over this wave's 16-key half (8 b128 reads, 2 chains) ----
    const unsigned short* kl = &lds_all[cur * 8192];
    const int krow = kh * 16 + l15;
    const int sw = (krow & 7) << 3;
    const unsigned short* kbase = kl + krow * 256;
    f32x4 a0 = (f32x4){0.f, 0.f, 0.f, 0.f};
    f32x4 a1 = (f32x4){0.f, 0.f, 0.f, 0.f};
    __builtin_amdgcn_s_setprio(1);
    #pragma unroll
    for (int dk = 0; dk < 4; ++dk) {
      s16x8 k0 = *(const s16x8*)(kbase + ((dk * 64 + lg * 8) ^ sw));
      s16x8 k1 = *(const s16x8*)(kbase + ((dk * 64 + 32 + lg * 8) ^ sw));
      a0 = __builtin_amdgcn_mfma_f32_16x16x32_bf16(
          __builtin_bit_cast(bf16x8_t, k0),
          __builtin_bit_cast(bf16x8_t, qf[2 * dk]), a0, 0, 0, 0);
      a1 = __builtin_amdgcn_mfma_f32_16x16x32_bf16(
          __builtin_bit_cast(bf16x8_t, k1),
          __builtin_bit_cast(bf16x8_t, qf[2 * dk + 1]), a1, 0, 0, 0);
    }
    __builtin_amdgcn_s_setprio(0);
    f32x4 s = a0 + a1;

    // ---- scale + key mask (k = t*32 + kh*16 + lg*4 + j) ----
    {
      int gk = t * 32 + kh * 16 + lg * 4;
      #pragma unroll
      for (int j2 = 0; j2 < 4; ++j2)
        s[j2] = (gk + j2 < n_k) ? s[j2] * 0.0625f : MINF;
    }

    // ---- softmax: shfl-free common path; full reduce only on rescale ----
    float pml = fmaxf(fmaxf(s[0], s[1]), fmaxf(s[2], s[3]));   // per-lane max
    if (__any(pml > m + 8.0f)) {
      float pm = fmaxf(pml, __shfl_xor(pml, 16, 64));
      pm = fmaxf(pm, __shfl_xor(pm, 32, 64));
      float mn = fmaxf(m, pm);
      float sc = __expf(m - mn);   // first tile: exp(-huge)=0
      m = mn; l *= sc;
      #pragma unroll
      for (int c = 0; c < 16; ++c) o[c] = o[c] * sc;
    }
    float p[4];
    #pragma unroll
    for (int j2 = 0; j2 < 4; ++j2) p[j2] = __expf(s[j2] - m);
    l += (p[0] + p[1]) + (p[2] + p[3]);    // per-lane partial; no shfl here

    // ---- P stays in-lane: C-frag(S^T) == B-frag(x16 PV) ----
    s16x4 pb;
    pb[0] = (short)f2bf(p[0]); pb[1] = (short)f2bf(p[1]);
    pb[2] = (short)f2bf(p[2]); pb[3] = (short)f2bf(p[3]);

    // ---- O^T += V^T P over this wave's 16 keys (16 x16-MFMAs, padded rows) ----
    const unsigned short* vl_ = &lds_all[16384 + cur * VTS];
    const int voff = (kh * 2 + (lg >> 1)) * 8 + (lg & 1) * 4;  // k-chunk offset
    __builtin_amdgcn_s_setprio(1);
    #pragma unroll
    for (int c = 0; c < 16; ++c) {
      int dv = c * 16 + l15;
      s16x4 vf = *(const s16x4*)(vl_ + dv * VSTR + voff);
      o[c] = mfma16(vf, pb, o[c]);
    }
    __builtin_amdgcn_s_setprio(0);

    __builtin_amdgcn_sched_barrier(0);
    __builtin_amdgcn_s_barrier();   // all reads of cur done -> reusable
  }

  // ---- reduce per-lane l to row totals (once), then merge kh halves ----
  l += __shfl_xor(l, 16, 64);
  l += __shfl_xor(l, 32, 64);
  __syncthreads();
  float* mo = (float*)lds_all + rq * 4192;   // [16 q][260] + m@4160 l@4176
  if (kh == 1) {
    #pragma unroll
    for (int c = 0; c < 16; ++c)
      *(f32x4*)(mo + l15 * 260 + c * 16 + lg * 4) = o[c];
    mo[4160 + l15] = m;    // lg-dup write, same value (benign)
    mo[4176 + l15] = l;
  }
  __syncthreads();
  if (kh == 0) {
    float mb = mo[4160 + l15];
    float lb = mo[4176 + l15];
    float M  = fmaxf(m, mb);
    float sa = __expf(m - M), sb = __expf(mb - M);
    float invL = 1.0f / (sa * l + sb * lb);
    float* ob = O + ((size_t)b * LQ_ + qbase + l15) * DV_;
    #pragma unroll
    for (int c = 0; c < 16; ++c) {
      f32x4 mr = *(const f32x4*)(mo + l15 * 260 + c * 16 + lg * 4);
      f32x4 r;
      #pragma unroll
      for (int j2 = 0; j2 < 4; ++j2)
        r[j2] = (sa * o[c][j2] + sb * mr[j2]) * invL;
      *(f32x4*)(ob + c * 16 + lg * 4) = r;
    }
  }
#undef STAGE
}

// ---------- fallback (round-1 kernel, used if ws too small) ----------
__global__ __launch_bounds__(256) void attn_fwd(
    const float* __restrict__ Q, const float* __restrict__ K,
    const float* __restrict__ V, const int* __restrict__ VL,
    float* __restrict__ O) {
  __shared__ __align__(16) unsigned short lds_k[64 * D_];
  __shared__ __align__(16) unsigned short lds_v[DV_ * 64];
  __shared__ __align__(16) unsigned short lds_p[4][16 * 64];

  const int tid  = threadIdx.x;
  const int wid  = tid >> 6;
  const int lane = tid & 63;
  const int l15  = lane & 15;
  const int lg   = lane >> 4;
  const int bid = blockIdx.x;
  const int b   = bid >> 5;
  const int qt  = bid & 31;

  int n_k = (VL[1] == 0) ? VL[2 * b] : VL[b];
  if (n_k < 1) n_k = 1;
  if (n_k > LK_) n_k = LK_;

  const int qbase = qt * 64 + wid * 16;
  s16x8 qf[8];
  {
    const float* qp = Q + ((size_t)b * LQ_ + qbase + l15) * D_ + lg * 8;
    #pragma unroll
    for (int dk = 0; dk < 8; ++dk) {
      float4 a = *(const float4*)(qp + dk * 32);
      float4 c = *(const float4*)(qp + dk * 32 + 4);
      qf[dk] = pack8(a, c);
    }
  }
  f32x4 o[16];
  #pragma unroll
  for (int c = 0; c < 16; ++c) o[c] = (f32x4){0.f, 0.f, 0.f, 0.f};
  float m[4]    = {-INFINITY, -INFINITY, -INFINITY, -INFINITY};
  float lsum[4] = {0.f, 0.f, 0.f, 0.f};
  const float* kb = K + (size_t)b * LK_ * D_;
  const float* vb = V + (size_t)b * LK_ * DV_;
  const int nt = (n_k + 63) / 64;

  for (int kt = 0; kt < nt; ++kt) {
    __syncthreads();
    {
      const float* src = kb + (size_t)kt * 64 * D_;
      #pragma unroll
      for (int p = 0; p < 8; ++p) {
        int e = (p * 256 + tid) * 8;
        int r = e >> 8;
        int d = e & 255;
        float4 a = *(const float4*)(src + e);
        float4 c = *(const float4*)(src + e + 4);
        *(s16x8*)(&lds_k[r * 256 + (d ^ ((r & 7) << 3))]) = pack8(a, c);
      }
    }
    {
      const float* src = vb + (size_t)kt * 64 * DV_;
      #pragma unroll
      for (int p = 0; p < 2; ++p) {
        int item = p * 256 + tid;
        int k0  = (item >> 5) * 4;
        int dv0 = (item & 31) * 8;
        float va[4][8];
        #pragma unroll
        for (int r = 0; r < 4; ++r) {
          float4 x = *(const float4*)(src + (k0 + r) * DV_ + dv0);
          float4 y = *(const float4*)(src + (k0 + r) * DV_ + dv0 + 4);
          va[r][0]=x.x; va[r][1]=x.y; va[r][2]=x.z; va[r][3]=x.w;
          va[r][4]=y.x; va[r][5]=y.y; va[r][6]=y.z; va[r][7]=y.w;
        }
        #pragma unroll
        for (int i = 0; i < 8; ++i) {
          int dv = dv0 + i;
          s16x4 w;
          w[0]=(short)f2bf(va[0][i]); w[1]=(short)f2bf(va[1][i]);
          w[2]=(short)f2bf(va[2][i]); w[3]=(short)f2bf(va[3][i]);
          *(s16x4*)(&lds_v[dv * 64 + (k0 ^ ((dv & 7) << 3))]) = w;
        }
      }
    }
    __syncthreads();

    f32x4 s[4];
    #pragma unroll
    for (int kc = 0; kc < 4; ++kc) {
      f32x4 acc = (f32x4){0.f, 0.f, 0.f, 0.f};
      int krow = kc * 16 + l15;
      int sw = (krow & 7) << 3;
      #pragma unroll
      for (int dk = 0; dk < 8; ++dk) {
        s16x8 kf = *(const s16x8*)(&lds_k[krow * 256 + ((dk * 32 + lg * 8) ^ sw)]);
        acc = __builtin_amdgcn_mfma_f32_16x16x32_bf16(
            __builtin_bit_cast(bf16x8_t, qf[dk]),
            __builtin_bit_cast(bf16x8_t, kf), acc, 0, 0, 0);
      }
      s[kc] = acc;
    }
    #pragma unroll
    for (int kc = 0; kc < 4; ++kc) {
      int gk = kt * 64 + kc * 16 + l15;
      #pragma unroll
      for (int j = 0; j < 4; ++j) {
        float v = s[kc][j] * 0.0625f;
        s[kc][j] = (gk < n_k) ? v : -INFINITY;
      }
    }
    float pm[4];
    #pragma unroll
    for (int j = 0; j < 4; ++j)
      pm[j] = fmaxf(fmaxf(s[0][j], s[1][j]), fmaxf(s[2][j], s[3][j]));
    #pragma unroll
    for (int off = 1; off < 16; off <<= 1) {
      #pragma unroll
      for (int j = 0; j < 4; ++j)
        pm[j] = fmaxf(pm[j], __shfl_xor(pm[j], off, 64));
    }
    float sc[4];
    #pragma unroll
    for (int j = 0; j < 4; ++j) {
      float mn = fmaxf(m[j], pm[j]);
      sc[j] = __expf(m[j] - mn);
      m[j] = mn;
    }
    float psum[4] = {0.f, 0.f, 0.f, 0.f};
    #pragma unroll
    for (int kc = 0; kc < 4; ++kc) {
      #pragma unroll
      for (int j = 0; j < 4; ++j) {
        float p = __expf(s[kc][j] - m[j]);
        psum[j] += p;
        int r2 = lg * 4 + j;
        lds_p[wid][r2 * 64 + ((kc * 16 + l15) ^ ((r2 & 7) << 3))] = f2bf(p);
      }
    }
    #pragma unroll
    for (int off = 1; off < 16; off <<= 1) {
      #pragma unroll
      for (int j = 0; j < 4; ++j)
        psum[j] += __shfl_xor(psum[j], off, 64);
    }
    #pragma unroll
    for (int j = 0; j < 4; ++j) lsum[j] = lsum[j] * sc[j] + psum[j];
    #pragma unroll
    for (int c = 0; c < 16; ++c) {
      #pragma unroll
      for (int j = 0; j < 4; ++j) o[c][j] *= sc[j];
    }
    s16x8 pa[2];
    #pragma unroll
    for (int kk = 0; kk < 2; ++kk)
      pa[kk] = *(const s16x8*)(&lds_p[wid][l15 * 64 + ((kk * 32 + lg * 8) ^ ((l15 & 7) << 3))]);
    #pragma unroll
    for (int c = 0; c < 16; ++c) {
      #pragma unroll
      for (int kk = 0; kk < 2; ++kk) {
        int dv = c * 16 + l15;
        s16x8 vf = *(const s16x8*)(&lds_v[dv * 64 + ((kk * 32 + lg * 8) ^ ((dv & 7) << 3))]);
        o[c] = __builtin_amdgcn_mfma_f32_16x16x32_bf16(
            __builtin_bit_cast(bf16x8_t, pa[kk]),
            __builtin_bit_cast(bf16x8_t, vf), o[c], 0, 0, 0);
      }
    }
  }
  float inv[4];
  #pragma unroll
  for (int j = 0; j < 4; ++j) inv[j] = 1.0f / lsum[j];
  float* ob = O + ((size_t)b * LQ_ + qbase) * DV_;
  #pragma unroll
  for (int c = 0; c < 16; ++c) {
    #pragma unroll
    for (int j = 0; j < 4; ++j) {
      int r2 = lg * 4 + j;
      ob[(size_t)r2 * DV_ + c * 16 + l15] = o[c][j] * inv[j];
    }
  }
}

extern "C" void kernel_launch(void* const* d_in, const int* in_sizes, int n_in,
                              void* d_out, int out_size, void* d_ws, size_t ws_size,
                              hipStream_t stream) {
  const float* Q  = (const float*)d_in[0];
  const float* K  = (const float*)d_in[1];
  const float* V  = (const float*)d_in[2];
  const int*   VL = (const int*)d_in[3];
  float* O = (float*)d_out;

  const size_t k_elems = (size_t)B_ * LK_ * D_;        // 8,388,608 shorts
  const size_t v_elems = (size_t)B_ * 64 * VTS;        // 9,437,184 shorts
  const size_t need = (k_elems + v_elems) * sizeof(unsigned short) + 2048;
  if (ws_size >= need) {
    unsigned short* wsK = (unsigned short*)d_ws;
    unsigned short* wsV = wsK + k_elems;
    int* sched = (int*)(wsV + v_elems);
    prep_sched<<<dim3(1), dim3(256), 0, stream>>>(VL, sched);
    prep_k<<<dim3(4096), dim3(256), 0, stream>>>(K, wsK);
    prep_v<<<dim3(1024), dim3(256), 0, stream>>>(V, wsV);
    attn_fwd9<<<dim3(512), dim3(512), 0, stream>>>(Q, wsK, wsV, VL, sched, O);
  } else {
    attn_fwd<<<dim3(512), dim3(256), 0, stream>>>(Q, K, V, VL, O);
  }
}

// Round 10
// 139.883 us; speedup vs baseline: 1.2976x; 1.2976x over previous
//
#include <hip/hip_runtime.h>
#include <hip/hip_bf16.h>

#define B_   16
#define LQ_  2048
#define LK_  2048
#define D_   256
#define DV_  256
#define MINF -1.0e30f

typedef __bf16 bf16x8_t __attribute__((ext_vector_type(8)));
typedef short  s16x8    __attribute__((ext_vector_type(8)));
typedef short  s16x4    __attribute__((ext_vector_type(4)));
typedef float  f32x4    __attribute__((ext_vector_type(4)));

__device__ __forceinline__ unsigned short f2bf(float f) {
  unsigned int u = __builtin_bit_cast(unsigned int, f);
  u += 0x7fffu + ((u >> 16) & 1u);   // RNE (finite inputs)
  return (unsigned short)(u >> 16);
}

__device__ __forceinline__ s16x8 pack8(float4 a, float4 b) {
  s16x8 r;
  r[0] = (short)f2bf(a.x); r[1] = (short)f2bf(a.y);
  r[2] = (short)f2bf(a.z); r[3] = (short)f2bf(a.w);
  r[4] = (short)f2bf(b.x); r[5] = (short)f2bf(b.y);
  r[6] = (short)f2bf(b.z); r[7] = (short)f2bf(b.w);
  return r;
}

__device__ __forceinline__ void glds16(const unsigned short* g, unsigned short* l) {
  __builtin_amdgcn_global_load_lds(
      (const __attribute__((address_space(1))) unsigned int*)g,
      (__attribute__((address_space(3))) unsigned int*)l, 16, 0, 0);
}

// ---------- prepass: K -> bf16, row-major, chunk-XOR pre-swizzled ----------
__global__ __launch_bounds__(256) void prep_k(const float* __restrict__ K,
                                              unsigned short* __restrict__ wsK) {
  int gid = blockIdx.x * 256 + threadIdx.x;
  int gr = gid >> 5;
  int c  = gid & 31;
  const float* src = K + ((size_t)gr << 8) + c * 8;
  float4 a = *(const float4*)(src);
  float4 b = *(const float4*)(src + 4);
  *(s16x8*)(wsK + ((size_t)gr << 8) + ((c ^ (gr & 7)) << 3)) = pack8(a, b);
}

// ---------- prepass: V -> bf16, transposed per 64-key tile, 8-chunk-XOR ----
// ws[tile*16384 + dv*64 + ((ch ^ (dv&7))<<3) + e] = bf16(V[tile*64 + ch*8+e][dv])
__global__ __launch_bounds__(256) void prep_v(const float* __restrict__ V,
                                              unsigned short* __restrict__ wsV) {
  __shared__ unsigned short t[256 * 72];
  const int tid = threadIdx.x;
  const float* src = V + (size_t)blockIdx.x * 64 * 256;
  #pragma unroll
  for (int i = 0; i < 16; ++i) {
    int idx = i * 256 + tid;
    int k   = idx >> 6;
    int dv0 = (idx & 63) * 4;
    float4 x = *(const float4*)(src + k * 256 + dv0);
    t[(dv0 + 0) * 72 + k] = f2bf(x.x);
    t[(dv0 + 1) * 72 + k] = f2bf(x.y);
    t[(dv0 + 2) * 72 + k] = f2bf(x.z);
    t[(dv0 + 3) * 72 + k] = f2bf(x.w);
  }
  __syncthreads();
  unsigned short* dst = wsV + (size_t)blockIdx.x * 16384;
  #pragma unroll
  for (int i = 0; i < 8; ++i) {
    int idx = i * 256 + tid;
    int dv = idx >> 3;
    int ch = idx & 7;
    s16x8 v = *(const s16x8*)(&t[dv * 72 + ch * 8]);
    *(s16x8*)(dst + dv * 64 + ((ch ^ (dv & 7)) << 3)) = v;
  }
}

// ---------- prepass: min-max-paired persistent schedule ----------
// desc[i] = i-th longest unit (batch ord[i>>5], qt = i&31).
// Worker w runs desc[w] then desc[511-w]  -> near-constant load.
__global__ __launch_bounds__(256) void prep_sched(const int* __restrict__ VL,
                                                  int* __restrict__ sched) {
  __shared__ int ord[16];
  if (threadIdx.x == 0) {
    int nk[16], o[16];
    const int wide = (VL[1] == 0);
    for (int i = 0; i < 16; ++i) {
      int v = wide ? VL[2 * i] : VL[i];
      if (v < 1) v = 1;
      if (v > LK_) v = LK_;
      nk[i] = v; o[i] = i;
    }
    for (int i = 1; i < 16; ++i) {           // insertion sort, desc by nk
      int key = o[i], kv = nk[key], j = i - 1;
      while (j >= 0 && nk[o[j]] < kv) { o[j + 1] = o[j]; --j; }
      o[j + 1] = key;
    }
    for (int i = 0; i < 16; ++i) ord[i] = o[i];
  }
  __syncthreads();
  for (int s = threadIdx.x; s < 512; s += 256) {
    int w  = s & 255;
    int un = s >> 8;
    int i  = un ? (511 - w) : w;             // desc index
    int bsel = ord[i >> 5];
    int qt   = i & 31;
    sched[s] = bsel | (qt << 8);
  }
}

// ---------- main v10: persistent 4-wave workers (2 rq x 2 kh), QB=64, KB=64 ----
// LDS shorts: K dbuf [0,32768), V dbuf [32768,65536), P [65536,70144). 140 KB.
__global__ __launch_bounds__(256, 1) void attn_fwd10(
    const float* __restrict__ Q, const unsigned short* __restrict__ wsK,
    const unsigned short* __restrict__ wsV, const int* __restrict__ VL,
    const int* __restrict__ sched, float* __restrict__ O) {
  __shared__ __align__(16) unsigned short lds_all[70144];

  const int tid  = threadIdx.x;
  const int wid  = tid >> 6;
  const int lane = tid & 63;
  const int l15  = lane & 15;
  const int lg   = lane >> 4;
  const int rq   = wid & 1;        // q sub-tile (32 rows)
  const int kh   = wid >> 1;       // key half (32 keys) of the 64-key tile

  unsigned short* pw = &lds_all[65536 + wid * 1152];   // [32 q][36] bf16

#define STAGE(buf, t) do {                                                    \
    const unsigned short* ks_ = kbw + (size_t)(t) * 16384;                    \
    const unsigned short* vs_ = vbw + (size_t)(t) * 16384;                    \
    _Pragma("unroll")                                                         \
    for (int p = 0; p < 8; ++p) {                                             \
      int cu = p * 256 + wid * 64;                                            \
      glds16(ks_ + (size_t)(cu + lane) * 8, &lds_all[(buf) * 16384 + cu * 8]);\
      glds16(vs_ + (size_t)(cu + lane) * 8,                                   \
             &lds_all[32768 + (buf) * 16384 + cu * 8]);                       \
    }                                                                         \
  } while (0)

  for (int un = 0; un < 2; ++un) {
    const int e  = sched[blockIdx.x + un * 256];
    const int b  = e & 255;
    const int qt = e >> 8;

    int n_k = (VL[1] == 0) ? VL[2 * b] : VL[b];
    if (n_k < 1) n_k = 1;
    if (n_k > LK_) n_k = LK_;
    const int nt = (n_k + 63) >> 6;

    const int qbase = qt * 64 + rq * 32;

    // Q fragments: qf[qc][dk] = Q[qbase+qc*16+l15][dk*32 + lg*8 .. +8]
    s16x8 qf[2][8];
    #pragma unroll
    for (int qc = 0; qc < 2; ++qc) {
      const float* qp = Q + ((size_t)b * LQ_ + qbase + qc * 16 + l15) * D_ + lg * 8;
      #pragma unroll
      for (int dk = 0; dk < 8; ++dk) {
        float4 a = *(const float4*)(qp + dk * 32);
        float4 c = *(const float4*)(qp + dk * 32 + 4);
        qf[qc][dk] = pack8(a, c);
      }
    }

    f32x4 o[2][16];
    #pragma unroll
    for (int qc = 0; qc < 2; ++qc)
      #pragma unroll
      for (int c = 0; c < 16; ++c) o[qc][c] = (f32x4){0.f, 0.f, 0.f, 0.f};
    float m[2] = {MINF, MINF}, l[2] = {0.f, 0.f};   // l = per-lane partials

    const unsigned short* kbw = wsK + (size_t)b * LK_ * D_;
    const unsigned short* vbw = wsV + (size_t)b * LK_ * DV_;

    __syncthreads();           // prior unit's overlay/LDS reads fully done
    STAGE(0, 0);               // 16 loads in flight

    for (int t = 0; t < nt; ++t) {
      const int cur = t & 1;
      if (t + 1 < nt) {
        STAGE(cur ^ 1, t + 1);                             // 32 in flight
        asm volatile("s_waitcnt vmcnt(16)" ::: "memory");  // tile t landed
      } else {
        asm volatile("s_waitcnt vmcnt(0)" ::: "memory");
      }
      __builtin_amdgcn_s_barrier();
      __builtin_amdgcn_sched_barrier(0);

      // ---- S^T = K Q^T over this wave's 32-key half, 2 qc sub-tiles ----
      const unsigned short* kl = &lds_all[cur * 16384];
      f32x4 s[2][2];
      __builtin_amdgcn_s_setprio(1);
      #pragma unroll
      for (int kc = 0; kc < 2; ++kc) {
        int krow = kh * 32 + kc * 16 + l15;
        int sw = (krow & 7) << 3;
        const unsigned short* kbase = kl + krow * 256;
        f32x4 a0 = (f32x4){0.f, 0.f, 0.f, 0.f};
        f32x4 a1 = (f32x4){0.f, 0.f, 0.f, 0.f};
        #pragma unroll
        for (int dk = 0; dk < 8; ++dk) {
          s16x8 kf = *(const s16x8*)(kbase + ((dk * 32 + lg * 8) ^ sw));
          a0 = __builtin_amdgcn_mfma_f32_16x16x32_bf16(
              __builtin_bit_cast(bf16x8_t, kf),
              __builtin_bit_cast(bf16x8_t, qf[0][dk]), a0, 0, 0, 0);
          a1 = __builtin_amdgcn_mfma_f32_16x16x32_bf16(
              __builtin_bit_cast(bf16x8_t, kf),
              __builtin_bit_cast(bf16x8_t, qf[1][dk]), a1, 0, 0, 0);
        }
        s[kc][0] = a0;
        s[kc][1] = a1;
      }
      __builtin_amdgcn_s_setprio(0);

      // ---- scale + key mask (rows = keys: gk = t*64 + kh*32 + kc*16 + lg*4+j)
      #pragma unroll
      for (int kc = 0; kc < 2; ++kc) {
        int gk = t * 64 + kh * 32 + kc * 16 + lg * 4;
        #pragma unroll
        for (int qc = 0; qc < 2; ++qc)
          #pragma unroll
          for (int j2 = 0; j2 < 4; ++j2)
            s[kc][qc][j2] = (gk + j2 < n_k) ? s[kc][qc][j2] * 0.0625f : MINF;
      }

      // ---- softmax: shfl-free common path; reduce only on rescale ----
      float pml[2];
      #pragma unroll
      for (int qc = 0; qc < 2; ++qc) {
        float v = fmaxf(fmaxf(s[0][qc][0], s[0][qc][1]),
                        fmaxf(s[0][qc][2], s[0][qc][3]));
        v = fmaxf(v, fmaxf(fmaxf(s[1][qc][0], s[1][qc][1]),
                           fmaxf(s[1][qc][2], s[1][qc][3])));
        pml[qc] = v;
      }
      if (__any((pml[0] > m[0] + 8.0f) || (pml[1] > m[1] + 8.0f))) {
        #pragma unroll
        for (int qc = 0; qc < 2; ++qc) {
          float pm = fmaxf(pml[qc], __shfl_xor(pml[qc], 16, 64));
          pm = fmaxf(pm, __shfl_xor(pm, 32, 64));
          float mn = fmaxf(m[qc], pm);
          float sc = __expf(m[qc] - mn);   // first tile: exp(-huge)=0
          m[qc] = mn; l[qc] *= sc;
          #pragma unroll
          for (int c = 0; c < 16; ++c) o[qc][c] = o[qc][c] * sc;
        }
      }
      #pragma unroll
      for (int qc = 0; qc < 2; ++qc) {
        float p[2][4];
        #pragma unroll
        for (int kc = 0; kc < 2; ++kc)
          #pragma unroll
          for (int j2 = 0; j2 < 4; ++j2)
            p[kc][j2] = __expf(s[kc][qc][j2] - m[qc]);
        l[qc] += ((p[0][0] + p[0][1]) + (p[0][2] + p[0][3]))
               + ((p[1][0] + p[1][1]) + (p[1][2] + p[1][3]));
        // store P^T rows: [q=qc*16+l15][k' = kc*16 + lg*4 ..+4], stride 36
        #pragma unroll
        for (int kc = 0; kc < 2; ++kc) {
          s16x4 w;
          w[0] = (short)f2bf(p[kc][0]); w[1] = (short)f2bf(p[kc][1]);
          w[2] = (short)f2bf(p[kc][2]); w[3] = (short)f2bf(p[kc][3]);
          *(s16x4*)(pw + (qc * 16 + l15) * 36 + kc * 16 + lg * 4) = w;
        }
      }

      // ---- P^T B-fragments (same-wave LDS round-trip) ----
      s16x8 pb[2];
      #pragma unroll
      for (int qc = 0; qc < 2; ++qc)
        pb[qc] = *(const s16x8*)(pw + (qc * 16 + l15) * 36 + lg * 8);

      // ---- O^T += V^T P^T over this wave's 32 keys ----
      const unsigned short* vl_ = &lds_all[32768 + cur * 16384];
      __builtin_amdgcn_s_setprio(1);
      #pragma unroll
      for (int c = 0; c < 16; ++c) {
        int dv = c * 16 + l15;
        s16x8 vf = *(const s16x8*)(vl_ + dv * 64 + (((kh * 4 + lg) ^ (dv & 7)) << 3));
        o[0][c] = __builtin_amdgcn_mfma_f32_16x16x32_bf16(
            __builtin_bit_cast(bf16x8_t, vf),
            __builtin_bit_cast(bf16x8_t, pb[0]), o[0][c], 0, 0, 0);
        o[1][c] = __builtin_amdgcn_mfma_f32_16x16x32_bf16(
            __builtin_bit_cast(bf16x8_t, vf),
            __builtin_bit_cast(bf16x8_t, pb[1]), o[1][c], 0, 0, 0);
      }
      __builtin_amdgcn_s_setprio(0);

      __builtin_amdgcn_sched_barrier(0);
      __builtin_amdgcn_s_barrier();   // all reads of cur done -> reusable
    }

    // ---- reduce per-lane l across lg groups (q = l15 fixed) ----
    #pragma unroll
    for (int qc = 0; qc < 2; ++qc) {
      l[qc] += __shfl_xor(l[qc], 16, 64);
      l[qc] += __shfl_xor(l[qc], 32, 64);
    }

    // ---- merge kh halves (overlay on staging LDS) ----
    __syncthreads();
    float* mo = (float*)lds_all + rq * 8448;   // [32 q][260] + m@8320 l@8352
    if (kh == 1) {
      #pragma unroll
      for (int qc = 0; qc < 2; ++qc) {
        #pragma unroll
        for (int c = 0; c < 16; ++c)
          *(f32x4*)(mo + (qc * 16 + l15) * 260 + c * 16 + lg * 4) = o[qc][c];
        mo[8320 + qc * 16 + l15] = m[qc];   // lg-dup writes, same value
        mo[8352 + qc * 16 + l15] = l[qc];
      }
    }
    __syncthreads();
    if (kh == 0) {
      #pragma unroll
      for (int qc = 0; qc < 2; ++qc) {
        float mb = mo[8320 + qc * 16 + l15];
        float lb = mo[8352 + qc * 16 + l15];
        float M  = fmaxf(m[qc], mb);
        float sa = __expf(m[qc] - M), sb = __expf(mb - M);
        float invL = 1.0f / (sa * l[qc] + sb * lb);
        float* ob = O + ((size_t)b * LQ_ + qbase + qc * 16 + l15) * DV_;
        #pragma unroll
        for (int c = 0; c < 16; ++c) {
          int dvb = c * 16 + lg * 4;
          f32x4 mr = *(const f32x4*)(mo + (qc * 16 + l15) * 260 + dvb);
          f32x4 r;
          #pragma unroll
          for (int j2 = 0; j2 < 4; ++j2)
            r[j2] = (sa * o[qc][c][j2] + sb * mr[j2]) * invL;
          *(f32x4*)(ob + dvb) = r;
        }
      }
    }
  }
#undef STAGE
}

// ---------- fallback (round-1 kernel, used if ws too small) ----------
__global__ __launch_bounds__(256) void attn_fwd(
    const float* __restrict__ Q, const float* __restrict__ K,
    const float* __restrict__ V, const int* __restrict__ VL,
    float* __restrict__ O) {
  __shared__ __align__(16) unsigned short lds_k[64 * D_];
  __shared__ __align__(16) unsigned short lds_v[DV_ * 64];
  __shared__ __align__(16) unsigned short lds_p[4][16 * 64];

  const int tid  = threadIdx.x;
  const int wid  = tid >> 6;
  const int lane = tid & 63;
  const int l15  = lane & 15;
  const int lg   = lane >> 4;
  const int bid = blockIdx.x;
  const int b   = bid >> 5;
  const int qt  = bid & 31;

  int n_k = (VL[1] == 0) ? VL[2 * b] : VL[b];
  if (n_k < 1) n_k = 1;
  if (n_k > LK_) n_k = LK_;

  const int qbase = qt * 64 + wid * 16;
  s16x8 qf[8];
  {
    const float* qp = Q + ((size_t)b * LQ_ + qbase + l15) * D_ + lg * 8;
    #pragma unroll
    for (int dk = 0; dk < 8; ++dk) {
      float4 a = *(const float4*)(qp + dk * 32);
      float4 c = *(const float4*)(qp + dk * 32 + 4);
      qf[dk] = pack8(a, c);
    }
  }
  f32x4 o[16];
  #pragma unroll
  for (int c = 0; c < 16; ++c) o[c] = (f32x4){0.f, 0.f, 0.f, 0.f};
  float m[4]    = {-INFINITY, -INFINITY, -INFINITY, -INFINITY};
  float lsum[4] = {0.f, 0.f, 0.f, 0.f};
  const float* kb = K + (size_t)b * LK_ * D_;
  const float* vb = V + (size_t)b * LK_ * DV_;
  const int nt = (n_k + 63) / 64;

  for (int kt = 0; kt < nt; ++kt) {
    __syncthreads();
    {
      const float* src = kb + (size_t)kt * 64 * D_;
      #pragma unroll
      for (int p = 0; p < 8; ++p) {
        int e = (p * 256 + tid) * 8;
        int r = e >> 8;
        int d = e & 255;
        float4 a = *(const float4*)(src + e);
        float4 c = *(const float4*)(src + e + 4);
        *(s16x8*)(&lds_k[r * 256 + (d ^ ((r & 7) << 3))]) = pack8(a, c);
      }
    }
    {
      const float* src = vb + (size_t)kt * 64 * DV_;
      #pragma unroll
      for (int p = 0; p < 2; ++p) {
        int item = p * 256 + tid;
        int k0  = (item >> 5) * 4;
        int dv0 = (item & 31) * 8;
        float va[4][8];
        #pragma unroll
        for (int r = 0; r < 4; ++r) {
          float4 x = *(const float4*)(src + (k0 + r) * DV_ + dv0);
          float4 y = *(const float4*)(src + (k0 + r) * DV_ + dv0 + 4);
          va[r][0]=x.x; va[r][1]=x.y; va[r][2]=x.z; va[r][3]=x.w;
          va[r][4]=y.x; va[r][5]=y.y; va[r][6]=y.z; va[r][7]=y.w;
        }
        #pragma unroll
        for (int i = 0; i < 8; ++i) {
          int dv = dv0 + i;
          s16x4 w;
          w[0]=(short)f2bf(va[0][i]); w[1]=(short)f2bf(va[1][i]);
          w[2]=(short)f2bf(va[2][i]); w[3]=(short)f2bf(va[3][i]);
          *(s16x4*)(&lds_v[dv * 64 + (k0 ^ ((dv & 7) << 3))]) = w;
        }
      }
    }
    __syncthreads();

    f32x4 s[4];
    #pragma unroll
    for (int kc = 0; kc < 4; ++kc) {
      f32x4 acc = (f32x4){0.f, 0.f, 0.f, 0.f};
      int krow = kc * 16 + l15;
      int sw = (krow & 7) << 3;
      #pragma unroll
      for (int dk = 0; dk < 8; ++dk) {
        s16x8 kf = *(const s16x8*)(&lds_k[krow * 256 + ((dk * 32 + lg * 8) ^ sw)]);
        acc = __builtin_amdgcn_mfma_f32_16x16x32_bf16(
            __builtin_bit_cast(bf16x8_t, qf[dk]),
            __builtin_bit_cast(bf16x8_t, kf), acc, 0, 0, 0);
      }
      s[kc] = acc;
    }
    #pragma unroll
    for (int kc = 0; kc < 4; ++kc) {
      int gk = kt * 64 + kc * 16 + l15;
      #pragma unroll
      for (int j = 0; j < 4; ++j) {
        float v = s[kc][j] * 0.0625f;
        s[kc][j] = (gk < n_k) ? v : -INFINITY;
      }
    }
    float pm[4];
    #pragma unroll
    for (int j = 0; j < 4; ++j)
      pm[j] = fmaxf(fmaxf(s[0][j], s[1][j]), fmaxf(s[2][j], s[3][j]));
    #pragma unroll
    for (int off = 1; off < 16; off <<= 1) {
      #pragma unroll
      for (int j = 0; j < 4; ++j)
        pm[j] = fmaxf(pm[j], __shfl_xor(pm[j], off, 64));
    }
    float sc[4];
    #pragma unroll
    for (int j = 0; j < 4; ++j) {
      float mn = fmaxf(m[j], pm[j]);
      sc[j] = __expf(m[j] - mn);
      m[j] = mn;
    }
    float psum[4] = {0.f, 0.f, 0.f, 0.f};
    #pragma unroll
    for (int kc = 0; kc < 4; ++kc) {
      #pragma unroll
      for (int j = 0; j < 4; ++j) {
        float p = __expf(s[kc][j] - m[j]);
        psum[j] += p;
        int r2 = lg * 4 + j;
        lds_p[wid][r2 * 64 + ((kc * 16 + l15) ^ ((r2 & 7) << 3))] = f2bf(p);
      }
    }
    #pragma unroll
    for (int off = 1; off < 16; off <<= 1) {
      #pragma unroll
      for (int j = 0; j < 4; ++j)
        psum[j] += __shfl_xor(psum[j], off, 64);
    }
    #pragma unroll
    for (int j = 0; j < 4; ++j) lsum[j] = lsum[j] * sc[j] + psum[j];
    #pragma unroll
    for (int c = 0; c < 16; ++c) {
      #pragma unroll
      for (int j = 0; j < 4; ++j) o[c][j] *= sc[j];
    }
    s16x8 pa[2];
    #pragma unroll
    for (int kk = 0; kk < 2; ++kk)
      pa[kk] = *(const s16x8*)(&lds_p[wid][l15 * 64 + ((kk * 32 + lg * 8) ^ ((l15 & 7) << 3))]);
    #pragma unroll
    for (int c = 0; c < 16; ++c) {
      #pragma unroll
      for (int kk = 0; kk < 2; ++kk) {
        int dv = c * 16 + l15;
        s16x8 vf = *(const s16x8*)(&lds_v[dv * 64 + ((kk * 32 + lg * 8) ^ ((dv & 7) << 3))]);
        o[c] = __builtin_amdgcn_mfma_f32_16x16x32_bf16(
            __builtin_bit_cast(bf16x8_t, pa[kk]),
            __builtin_bit_cast(bf16x8_t, vf), o[c], 0, 0, 0);
      }
    }
  }
  float inv[4];
  #pragma unroll
  for (int j = 0; j < 4; ++j) inv[j] = 1.0f / lsum[j];
  float* ob = O + ((size_t)b * LQ_ + qbase) * DV_;
  #pragma unroll
  for (int c = 0; c < 16; ++c) {
    #pragma unroll
    for (int j = 0; j < 4; ++j) {
      int r2 = lg * 4 + j;
      ob[(size_t)r2 * DV_ + c * 16 + l15] = o[c][j] * inv[j];
    }
  }
}

extern "C" void kernel_launch(void* const* d_in, const int* in_sizes, int n_in,
                              void* d_out, int out_size, void* d_ws, size_t ws_size,
                              hipStream_t stream) {
  const float* Q  = (const float*)d_in[0];
  const float* K  = (const float*)d_in[1];
  const float* V  = (const float*)d_in[2];
  const int*   VL = (const int*)d_in[3];
  float* O = (float*)d_out;

  const size_t kv_elems = (size_t)B_ * LK_ * D_;               // 8,388,608 each
  const size_t need = kv_elems * 2 * sizeof(unsigned short) + 2048;
  if (ws_size >= need) {
    unsigned short* wsK = (unsigned short*)d_ws;
    unsigned short* wsV = wsK + kv_elems;
    int* sched = (int*)(wsV + kv_elems);
    prep_sched<<<dim3(1), dim3(256), 0, stream>>>(VL, sched);
    prep_k<<<dim3(4096), dim3(256), 0, stream>>>(K, wsK);
    prep_v<<<dim3(512), dim3(256), 0, stream>>>(V, wsV);
    attn_fwd10<<<dim3(256), dim3(256), 0, stream>>>(Q, wsK, wsV, VL, sched, O);
  } else {
    attn_fwd<<<dim3(512), dim3(256), 0, stream>>>(Q, K, V, VL, O);
  }
}